// Round 3
// baseline (80.503 us; speedup 1.0000x reference)
//
#include <hip/hip_runtime.h>
#include <hip/hip_bf16.h>

#define BB 4096   // batch
#define DD 64     // event dim
#define HH 512    // hidden

typedef short short8 __attribute__((ext_vector_type(8)));   // 8 bf16
typedef float f32x4  __attribute__((ext_vector_type(4)));
typedef __hip_bfloat16 bf16;

// branchless fast tanh: 1 - 2/(1+e^{2x}); exact limits at +-inf
__device__ __forceinline__ float tanh_fast(float x) {
    float e = __expf(2.0f * x);
    return 1.0f - __fdividef(2.0f, 1.0f + e);
}

// swizzled LDS bf16 store: chunk(8 elems) XOR'd by row&7 (both-sides swizzle)
__device__ __forceinline__ void st_swz(bf16* base, int row, int col, int rs, float v) {
    base[row * rs + ((((col >> 3) ^ (row & 7))) << 3) + (col & 7)] = __float2bfloat16(v);
}

// ---------------------------------------------------------------------------
// prep kernel (385 blocks x 256): weight transposes to bf16 + P + b1eff
//  bx<256 : W2t[n][k] = bf16(W2[k][n])
//  <288   : W1t[j][d] = bf16(W1[d][j]) (d<64)
//  <320   : W3t[e][k] = bf16(W3[k][e])
//  <384   : Pt[k][j]  = bf16(W2[j][k] * sum_d W1[d][j]*W3[k][d])
//  ==384  : b1eff[j]  = b1[j] + t*W1[64][j]
// ---------------------------------------------------------------------------
__global__ __launch_bounds__(256) void prep_kernel(
    const float* __restrict__ t, const float* __restrict__ W1,
    const float* __restrict__ b1, const float* __restrict__ W2,
    const float* __restrict__ W3,
    bf16* __restrict__ W1t, bf16* __restrict__ W2t, bf16* __restrict__ W3t,
    bf16* __restrict__ Pt, float* __restrict__ b1eff)
{
    __shared__ float tile[32][33];
    const int tid = threadIdx.x;
    const int bx  = blockIdx.x;
    const int tx = tid & 31, ty = tid >> 5;   // 32 x 8

    if (bx < 256) {
        int r0 = (bx >> 4) * 32, c0 = (bx & 15) * 32;
#pragma unroll
        for (int i = 0; i < 32; i += 8)
            tile[ty + i][tx] = W2[(size_t)(r0 + ty + i) * HH + c0 + tx];
        __syncthreads();
#pragma unroll
        for (int i = 0; i < 32; i += 8)
            W2t[(size_t)(c0 + ty + i) * HH + r0 + tx] = __float2bfloat16(tile[tx][ty + i]);
    } else if (bx < 288) {
        int b = bx - 256;
        int r0 = (b >> 4) * 32, c0 = (b & 15) * 32;   // d-rows, j-cols
#pragma unroll
        for (int i = 0; i < 32; i += 8)
            tile[ty + i][tx] = W1[(size_t)(r0 + ty + i) * HH + c0 + tx];
        __syncthreads();
#pragma unroll
        for (int i = 0; i < 32; i += 8)
            W1t[(size_t)(c0 + ty + i) * DD + r0 + tx] = __float2bfloat16(tile[tx][ty + i]);
    } else if (bx < 320) {
        int b = bx - 288;
        int r0 = (b >> 1) * 32, c0 = (b & 1) * 32;    // k-rows, e-cols
#pragma unroll
        for (int i = 0; i < 32; i += 8)
            tile[ty + i][tx] = W3[(size_t)(r0 + ty + i) * DD + c0 + tx];
        __syncthreads();
#pragma unroll
        for (int i = 0; i < 32; i += 8)
            W3t[(size_t)(c0 + ty + i) * HH + r0 + tx] = __float2bfloat16(tile[tx][ty + i]);
    } else if (bx < 384) {
        int b = bx - 320;
        int k0 = b * 8;
        int j0 = tid * 2;
        float acc0[8] = {}, acc1[8] = {};
        for (int d = 0; d < 64; ++d) {
            float w1a = W1[(size_t)d * HH + j0];
            float w1b = W1[(size_t)d * HH + j0 + 1];
#pragma unroll
            for (int kk = 0; kk < 8; ++kk) {
                float w3 = W3[(size_t)(k0 + kk) * DD + d];
                acc0[kk] += w1a * w3;
                acc1[kk] += w1b * w3;
            }
        }
#pragma unroll
        for (int kk = 0; kk < 8; ++kk) {
            int k = k0 + kk;
            Pt[(size_t)k * HH + j0]     = __float2bfloat16(acc0[kk] * W2[(size_t)j0 * HH + k]);
            Pt[(size_t)k * HH + j0 + 1] = __float2bfloat16(acc1[kk] * W2[(size_t)(j0 + 1) * HH + k]);
        }
    } else {
        float tv = t[0];
        b1eff[tid]       = b1[tid]       + tv * W1[(size_t)64 * HH + tid];
        b1eff[tid + 256] = b1[tid + 256] + tv * W1[(size_t)64 * HH + tid + 256];
    }
}

// ---------------------------------------------------------------------------
// gemm_rows16: one wave computes a [16 x NI*16] output strip.
// A: swizzled LDS [32 x RS] bf16 (rows arow0..arow0+15). B: direct global
// (Bt row-major [N x K], per-ni lane pointers), prefetched PF deep in regs.
// ---------------------------------------------------------------------------
template <int NS, int NI, int RS>
__device__ __forceinline__ void gemm_rows16(
    const bf16* lds_a, int arow0, const bf16* const* pBn, int lane,
    f32x4* acc)
{
    const int r  = lane & 15;
    const int kq = lane >> 4;
    const int row = arow0 + r;
    const int rx = row & 7;
    const bf16* pa = lds_a + row * RS;

    constexpr int PF = (NS >= 4) ? 3 : NS;
    short8 bfr[PF][NI];
#pragma unroll
    for (int p = 0; p < PF; ++p)
#pragma unroll
        for (int ni = 0; ni < NI; ++ni)
            bfr[p][ni] = *(const short8*)(pBn[ni] + p * 32);

#pragma unroll
    for (int s = 0; s < NS; ++s) {
        short8 af = *(const short8*)(pa + ((((s << 2) | kq) ^ rx) << 3));
#pragma unroll
        for (int ni = 0; ni < NI; ++ni)
            acc[ni] = __builtin_amdgcn_mfma_f32_16x16x32_bf16(
                af, bfr[s % PF][ni], acc[ni], 0, 0, 0);
        if (s + PF < NS) {
#pragma unroll
            for (int ni = 0; ni < NI; ++ni)
                bfr[s % PF][ni] = *(const short8*)(pBn[ni] + (s + PF) * 32);
        }
    }
}

// ---------------------------------------------------------------------------
// mega kernel: 128 blocks x 512 threads; block = 32 batch rows through
// L1 -> L2 -> E -> L3 with h1/a/h2 entirely in LDS.
// Waves: 2M x 4N; wave = 16 rows x 128 cols for N=512 GEMMs; 16x16 for L3.
// ---------------------------------------------------------------------------
__global__ __launch_bounds__(512, 2) void mega_kernel(
    const float* __restrict__ z, const bf16* __restrict__ W1t,
    const bf16* __restrict__ W2t, const bf16* __restrict__ W3t,
    const bf16* __restrict__ Pt, const float* __restrict__ b1eff,
    const float* __restrict__ b2, const float* __restrict__ b3,
    float* __restrict__ outV, float* __restrict__ outTr)
{
    __shared__ alignas(16) bf16 zb[32 * 64];
    __shared__ alignas(16) bf16 h1s[32 * 512];
    __shared__ alignas(16) bf16 as_[32 * 512];
    __shared__ alignas(16) bf16 h2s[32 * 512];
    __shared__ float tr_part[8][32];

    const int tid  = threadIdx.x;
    const int wid  = tid >> 6;
    const int lane = tid & 63;
    const int r    = lane & 15;
    const int kq   = lane >> 4;
    const int wr   = wid >> 2;            // 0..1  (M split)
    const int wc   = wid & 3;             // 0..3  (N split)
    const int arow0   = wr * 16;
    const int colbase = wc * 128;
    const int bm   = blockIdx.x * 32;

    // ---- stage z (fp32 global -> bf16 swizzled LDS) ----
    {
        int row = tid >> 4, c = (tid & 15) * 4;
        float4 v = *(const float4*)(z + (size_t)(bm + row) * DD + c);
        st_swz(zb, row, c + 0, 64, v.x);
        st_swz(zb, row, c + 1, 64, v.y);
        st_swz(zb, row, c + 2, 64, v.z);
        st_swz(zb, row, c + 3, 64, v.w);
    }
    __syncthreads();

    // ---- L1: h1 = tanh(z @ W1 + b1eff); a = 1-h1^2 ----
    {
        const bf16* pBn[8];
#pragma unroll
        for (int ni = 0; ni < 8; ++ni)
            pBn[ni] = W1t + (size_t)(colbase + ni * 16 + r) * 64 + kq * 8;
        f32x4 acc[8] = {};
        gemm_rows16<2, 8, 64>(zb, arow0, pBn, lane, acc);
#pragma unroll
        for (int ni = 0; ni < 8; ++ni) {
            int col = colbase + ni * 16 + r;
            float bias = b1eff[col];
#pragma unroll
            for (int v = 0; v < 4; ++v) {
                int row = arow0 + kq * 4 + v;
                float h = tanh_fast(acc[ni][v] + bias);
                st_swz(h1s, row, col, 512, h);
                st_swz(as_, row, col, 512, fmaf(-h, h, 1.0f));
            }
        }
    }
    __syncthreads();

    // ---- L2: h2 = tanh(h1 @ W2 + b2); bsq kept in registers ----
    f32x4 bsq[8];
    {
        const bf16* pBn[8];
#pragma unroll
        for (int ni = 0; ni < 8; ++ni)
            pBn[ni] = W2t + (size_t)(colbase + ni * 16 + r) * HH + kq * 8;
        f32x4 acc[8] = {};
        gemm_rows16<16, 8, 512>(h1s, arow0, pBn, lane, acc);
#pragma unroll
        for (int ni = 0; ni < 8; ++ni) {
            int col = colbase + ni * 16 + r;
            float bias = b2[col];
#pragma unroll
            for (int v = 0; v < 4; ++v) {
                int row = arow0 + kq * 4 + v;
                float h = tanh_fast(acc[ni][v] + bias);
                st_swz(h2s, row, col, 512, h);
                bsq[ni][v] = fmaf(-h, h, 1.0f);
            }
        }
    }
    __syncthreads();

    // ---- E: V = a @ P; trace partial = sum_col V*bsq (same frag mapping) ----
    {
        const bf16* pBn[8];
#pragma unroll
        for (int ni = 0; ni < 8; ++ni)
            pBn[ni] = Pt + (size_t)(colbase + ni * 16 + r) * HH + kq * 8;
        f32x4 acc[8] = {};
        gemm_rows16<16, 8, 512>(as_, arow0, pBn, lane, acc);
#pragma unroll
        for (int v = 0; v < 4; ++v) {
            float p = 0.f;
#pragma unroll
            for (int ni = 0; ni < 8; ++ni)
                p += acc[ni][v] * bsq[ni][v];
            p += __shfl_xor(p, 1);
            p += __shfl_xor(p, 2);
            p += __shfl_xor(p, 4);
            p += __shfl_xor(p, 8);
            if (r == 0) tr_part[wid][arow0 + kq * 4 + v] = p;
        }
    }

    // ---- L3: v = h2 @ W3 + b3 (wave = 16x16 tile; wc picks col-16) ----
    {
        const bf16* pB3[1];
        pB3[0] = W3t + (size_t)(wc * 16 + r) * HH + kq * 8;
        f32x4 acc3 = {};
        gemm_rows16<16, 1, 512>(h2s, arow0, pB3, lane, &acc3);
        int col = wc * 16 + r;
        float bias = b3[col];
#pragma unroll
        for (int v = 0; v < 4; ++v) {
            int row = arow0 + kq * 4 + v;
            outV[(size_t)(bm + row) * DD + col] = acc3[v] + bias;
        }
    }
    __syncthreads();

    // ---- trace: sum the 4 N-partial waves per row, write out ----
    if (tid < 32) {
        int wbase = (tid >> 4) * 4;      // waves with wr == tid/16
        float s = tr_part[wbase + 0][tid] + tr_part[wbase + 1][tid] +
                  tr_part[wbase + 2][tid] + tr_part[wbase + 3][tid];
        outTr[bm + tid] = -s;
    }
}

extern "C" void kernel_launch(void* const* d_in, const int* in_sizes, int n_in,
                              void* d_out, int out_size, void* d_ws, size_t ws_size,
                              hipStream_t stream)
{
    const float* z  = (const float*)d_in[0];
    const float* t  = (const float*)d_in[2];
    const float* W1 = (const float*)d_in[3];
    const float* b1 = (const float*)d_in[4];
    const float* W2 = (const float*)d_in[5];
    const float* b2 = (const float*)d_in[6];
    const float* W3 = (const float*)d_in[7];
    const float* b3 = (const float*)d_in[8];
    float* out = (float*)d_out;                 // v [4096*64] then dlogp [4096]
    float* out_tr = out + (size_t)BB * DD;

    char* w = (char*)d_ws;
    auto alloc = [&](size_t bytes) {
        char* p = w;
        w += (bytes + 255) & ~(size_t)255;
        return p;
    };
    bf16* W1t   = (bf16*)alloc((size_t)HH * DD * 2);
    bf16* W2t   = (bf16*)alloc((size_t)HH * HH * 2);
    bf16* W3t   = (bf16*)alloc((size_t)DD * HH * 2);
    bf16* Pt    = (bf16*)alloc((size_t)HH * HH * 2);
    float* b1eff = (float*)alloc((size_t)HH * 4);

    prep_kernel<<<385, 256, 0, stream>>>(t, W1, b1, W2, W3,
                                         W1t, W2t, W3t, Pt, b1eff);
    mega_kernel<<<BB / 32, 512, 0, stream>>>(z, W1t, W2t, W3t, Pt,
                                             b1eff, b2, b3, out, out_tr);
}

// Round 4
// 37.691 us; speedup vs baseline: 2.1359x; 2.1359x over previous
//
#include <hip/hip_runtime.h>
#include <hip/hip_bf16.h>

#define BB 4096   // batch
#define DD 64     // event dim
#define HH 512    // hidden

typedef short short8 __attribute__((ext_vector_type(8)));   // 8 bf16
typedef float f32x4  __attribute__((ext_vector_type(4)));
typedef __hip_bfloat16 bf16;

// async global->LDS, 16B per lane; LDS dest is wave-uniform base + lane*16
#define GLOAD_LDS16(gp, lp)                                                \
  __builtin_amdgcn_global_load_lds(                                        \
      (const __attribute__((address_space(1))) void*)(gp),                 \
      (__attribute__((address_space(3))) void*)(lp), 16, 0, 0)

// branchless fast tanh: 1 - 2/(1+e^{2x}); exact limits at +-inf
__device__ __forceinline__ float tanh_fast(float x) {
    float e = __expf(2.0f * x);
    return 1.0f - __fdividef(2.0f, 1.0f + e);
}

// ---------------------------------------------------------------------------
// prep kernel: grid (256, 6) x 256 threads  (proven in round 2, ~0.3us)
//  y0: z f32 -> bf16 (vectorized)
//  y1: W2t[n][k] = bf16(W2[k][n])        (32x32 LDS-tiled transpose)
//  y2: W1t[j][d] = bf16(W1[d][j]) (d<64)
//  y3: W3t[e][k] = bf16(W3[k][e])
//  y4: Pt[k][j]  = bf16(W2[j][k] * sum_d W1[d][j]*W3[k][d])
//  y5: b1eff[j]  = b1[j] + t*W1[64][j]
// ---------------------------------------------------------------------------
__global__ __launch_bounds__(256) void prep_kernel(
    const float* __restrict__ z, const float* __restrict__ t,
    const float* __restrict__ W1, const float* __restrict__ b1,
    const float* __restrict__ W2, const float* __restrict__ W3,
    bf16* __restrict__ z_b, bf16* __restrict__ W1t, bf16* __restrict__ W2t,
    bf16* __restrict__ W3t, bf16* __restrict__ Pt, float* __restrict__ b1eff)
{
    __shared__ float tile[32][33];
    const int tid = threadIdx.x;
    const int bx  = blockIdx.x;
    const int sec = blockIdx.y;
    const int tx = tid & 31, ty = tid >> 5;   // 32 x 8

    if (sec == 0) {
        int i = (bx * 256 + tid) * 4;
        float4 v = *(const float4*)(z + i);
        z_b[i + 0] = __float2bfloat16(v.x);
        z_b[i + 1] = __float2bfloat16(v.y);
        z_b[i + 2] = __float2bfloat16(v.z);
        z_b[i + 3] = __float2bfloat16(v.w);
    } else if (sec == 1) {
        int r0 = (bx >> 4) * 32, c0 = (bx & 15) * 32;
#pragma unroll
        for (int i = 0; i < 32; i += 8)
            tile[ty + i][tx] = W2[(size_t)(r0 + ty + i) * HH + c0 + tx];
        __syncthreads();
#pragma unroll
        for (int i = 0; i < 32; i += 8)
            W2t[(size_t)(c0 + ty + i) * HH + r0 + tx] = __float2bfloat16(tile[tx][ty + i]);
    } else if (sec == 2) {
        if (bx < 32) {
            int r0 = (bx >> 4) * 32, c0 = (bx & 15) * 32;   // d-rows, j-cols
#pragma unroll
            for (int i = 0; i < 32; i += 8)
                tile[ty + i][tx] = W1[(size_t)(r0 + ty + i) * HH + c0 + tx];
            __syncthreads();
#pragma unroll
            for (int i = 0; i < 32; i += 8)
                W1t[(size_t)(c0 + ty + i) * DD + r0 + tx] = __float2bfloat16(tile[tx][ty + i]);
        }
    } else if (sec == 3) {
        if (bx < 32) {
            int r0 = (bx >> 1) * 32, c0 = (bx & 1) * 32;    // k-rows, e-cols
#pragma unroll
            for (int i = 0; i < 32; i += 8)
                tile[ty + i][tx] = W3[(size_t)(r0 + ty + i) * DD + c0 + tx];
            __syncthreads();
#pragma unroll
            for (int i = 0; i < 32; i += 8)
                W3t[(size_t)(c0 + ty + i) * HH + r0 + tx] = __float2bfloat16(tile[tx][ty + i]);
        }
    } else if (sec == 4) {
        if (bx < 64) {
            int k0 = bx * 8;
            int j0 = tid * 2;
            float acc0[8] = {}, acc1[8] = {};
            for (int d = 0; d < 64; ++d) {
                float w1a = W1[(size_t)d * HH + j0];
                float w1b = W1[(size_t)d * HH + j0 + 1];
#pragma unroll
                for (int kk = 0; kk < 8; ++kk) {
                    float w3 = W3[(size_t)(k0 + kk) * DD + d];
                    acc0[kk] += w1a * w3;
                    acc1[kk] += w1b * w3;
                }
            }
#pragma unroll
            for (int kk = 0; kk < 8; ++kk) {
                int k = k0 + kk;
                Pt[(size_t)k * HH + j0]     = __float2bfloat16(acc0[kk] * W2[(size_t)j0 * HH + k]);
                Pt[(size_t)k * HH + j0 + 1] = __float2bfloat16(acc1[kk] * W2[(size_t)(j0 + 1) * HH + k]);
            }
        }
    } else {
        if (bx == 0) {
            float tv = t[0];
            b1eff[tid]       = b1[tid]       + tv * W1[(size_t)64 * HH + tid];
            b1eff[tid + 256] = b1[tid + 256] + tv * W1[(size_t)64 * HH + tid + 256];
        }
    }
}

// ---------------------------------------------------------------------------
// GEMM body: C[M,N] = A[M,K] * Bt[N,K]^T. 64x64 block tile, BK=64.
// 4-deep LDS ring buffer, stage 2 tiles ahead via global_load_lds(16B),
// ONE raw s_barrier per K-step with counted vmcnt (never 0 mid-loop).
// XOR chunk-swizzle: linear LDS dest + inverse-swizzled global source +
// swizzled ds_read (both-sides, rule 21).
// 4 waves 2x2, each wave 32x32 via 2x2 mfma_f32_16x16x32_bf16.
//  EPI 0: h = tanh(acc+bias[col]) -> outH; 1-h^2 -> outA
//  EPI 1: outF = acc + bias[col]
//  EPI 2: trace: p_row = sum_col acc*bs; shfl-reduce; atomicAdd(outTr+row,-p)
// ---------------------------------------------------------------------------
template <int EPI, int K, int N>
__device__ __forceinline__ void gemm_body(
    const bf16* __restrict__ A, const bf16* __restrict__ Bt,
    const float* __restrict__ bias,
    bf16* __restrict__ outH, bf16* __restrict__ outA,
    const bf16* __restrict__ bs, float* __restrict__ outF,
    float* __restrict__ outTr,
    int bm, int bn, bf16* As, bf16* Bs)
{
    const int tid  = threadIdx.x;
    const int wid  = tid >> 6;
    const int lane = tid & 63;
    const int r    = lane & 15;
    const int kq   = lane >> 4;
    const int wm   = (wid >> 1) * 32;
    const int wn   = (wid & 1) * 32;

    // LDS read offsets (bf16 elements), swizzled chunk addressing
    int offA[2][2], offB[2][2];
#pragma unroll
    for (int mi = 0; mi < 2; ++mi) {
        int row = wm + mi * 16 + r;
#pragma unroll
        for (int ks = 0; ks < 2; ++ks)
            offA[mi][ks] = row * 64 + ((((ks * 4 + kq) ^ (row & 7))) << 3);
    }
#pragma unroll
    for (int ni = 0; ni < 2; ++ni) {
        int row = wn + ni * 16 + r;
#pragma unroll
        for (int ks = 0; ks < 2; ++ks)
            offB[ni][ks] = row * 64 + ((((ks * 4 + kq) ^ (row & 7))) << 3);
    }

    // per-thread staging source pattern: i = rnd*256+tid -> row=i>>3,
    // src chunk = (i&7) ^ (row&7); LDS dest linear (lane-contiguous 16B)
    const int i0   = tid;
    const int i1   = 256 + tid;
    const int row0 = i0 >> 3, row1 = i1 >> 3;
    const int c0   = ((i0 & 7) ^ (row0 & 7)) << 3;
    const int c1   = ((i1 & 7) ^ (row1 & 7)) << 3;
    const bf16* a_src0 = A  + (size_t)(bm + row0) * K + c0;
    const bf16* a_src1 = A  + (size_t)(bm + row1) * K + c1;
    const bf16* b_src0 = Bt + (size_t)(bn + row0) * K + c0;
    const bf16* b_src1 = Bt + (size_t)(bn + row1) * K + c1;

    auto stage = [&](int t) {        // t is compile-time after full unroll
        const int b  = t & 3;
        const int k0 = t * 64;
        GLOAD_LDS16(a_src0 + k0, As + b * 4096 + i0 * 8);
        GLOAD_LDS16(b_src0 + k0, Bs + b * 4096 + i0 * 8);
        GLOAD_LDS16(a_src1 + k0, As + b * 4096 + i1 * 8);
        GLOAD_LDS16(b_src1 + k0, Bs + b * 4096 + i1 * 8);
    };

    f32x4 acc[2][2] = {};
    constexpr int NS = K / 64;

    stage(0);
    if (NS > 1) stage(1);

#pragma unroll
    for (int t = 0; t < NS; ++t) {
        if (t + 2 < NS) stage(t + 2);
        // writer waits for its own tile-t loads, THEN all waves sync.
        if (t + 2 < NS)      asm volatile("s_waitcnt vmcnt(8)" ::: "memory");
        else if (t + 1 < NS) asm volatile("s_waitcnt vmcnt(4)" ::: "memory");
        else                 asm volatile("s_waitcnt vmcnt(0)" ::: "memory");
        __builtin_amdgcn_s_barrier();
        asm volatile("" ::: "memory");   // pin LDS reads below the barrier

        const bf16* a_base = As + (t & 3) * 4096;
        const bf16* b_base = Bs + (t & 3) * 4096;
        short8 af[2][2], bfr[2][2];
#pragma unroll
        for (int mi = 0; mi < 2; ++mi)
#pragma unroll
            for (int ks = 0; ks < 2; ++ks)
                af[mi][ks] = *(const short8*)(a_base + offA[mi][ks]);
#pragma unroll
        for (int ni = 0; ni < 2; ++ni)
#pragma unroll
            for (int ks = 0; ks < 2; ++ks)
                bfr[ni][ks] = *(const short8*)(b_base + offB[ni][ks]);
#pragma unroll
        for (int ks = 0; ks < 2; ++ks)
#pragma unroll
            for (int mi = 0; mi < 2; ++mi)
#pragma unroll
                for (int ni = 0; ni < 2; ++ni)
                    acc[mi][ni] = __builtin_amdgcn_mfma_f32_16x16x32_bf16(
                        af[mi][ks], bfr[ni][ks], acc[mi][ni], 0, 0, 0);
    }

    // epilogue
#pragma unroll
    for (int mi = 0; mi < 2; ++mi) {
        if (EPI == 2) {
#pragma unroll
            for (int v = 0; v < 4; ++v) {
                int row = bm + wm + mi * 16 + kq * 4 + v;
                float p = 0.f;
#pragma unroll
                for (int ni = 0; ni < 2; ++ni) {
                    int col = bn + wn + ni * 16 + r;
                    float bsv = __bfloat162float(bs[(size_t)row * N + col]);
                    p += acc[mi][ni][v] * bsv;
                }
                p += __shfl_xor(p, 1);
                p += __shfl_xor(p, 2);
                p += __shfl_xor(p, 4);
                p += __shfl_xor(p, 8);
                if (r == 0) atomicAdd(outTr + row, -p);
            }
        } else {
#pragma unroll
            for (int ni = 0; ni < 2; ++ni) {
#pragma unroll
                for (int v = 0; v < 4; ++v) {
                    int row = bm + wm + mi * 16 + kq * 4 + v;
                    int col = bn + wn + ni * 16 + r;
                    float val = acc[mi][ni][v] + bias[col];
                    size_t o = (size_t)row * N + col;
                    if (EPI == 0) {
                        float h = tanh_fast(val);
                        outH[o] = __float2bfloat16(h);
                        outA[o] = __float2bfloat16(fmaf(-h, h, 1.0f));
                    } else {
                        outF[o] = val;
                    }
                }
            }
        }
    }
}

template <int EPI, int K, int N>
__global__ __launch_bounds__(256) void gemm_kernel(
    const bf16* __restrict__ A, const bf16* __restrict__ Bt,
    const float* __restrict__ bias,
    bf16* __restrict__ outH, bf16* __restrict__ outA,
    const bf16* __restrict__ bs, float* __restrict__ outF,
    float* __restrict__ outTr)
{
    __shared__ alignas(16) bf16 As[4 * 4096];
    __shared__ alignas(16) bf16 Bs[4 * 4096];
    gemm_body<EPI, K, N>(A, Bt, bias, outH, outA, bs, outF, outTr,
                         blockIdx.x * 64, blockIdx.y * 64, As, Bs);
}

// fused: y==8 -> L3 (v = h2@W3 + b3), y<8 -> E (trace = rowsum((a@P).*bsq))
__global__ __launch_bounds__(256) void gemm_fused(
    const bf16* __restrict__ h2b, const bf16* __restrict__ W3t,
    const float* __restrict__ b3, float* __restrict__ outV,
    const bf16* __restrict__ ab, const bf16* __restrict__ Pt,
    const bf16* __restrict__ bsb, float* __restrict__ outTr)
{
    __shared__ alignas(16) bf16 As[4 * 4096];
    __shared__ alignas(16) bf16 Bs[4 * 4096];
    if (blockIdx.y == 8) {
        gemm_body<1, 512, 64>(h2b, W3t, b3, nullptr, nullptr, nullptr, outV,
                              nullptr, blockIdx.x * 64, 0, As, Bs);
    } else {
        gemm_body<2, 512, 512>(ab, Pt, nullptr, nullptr, nullptr, bsb, nullptr,
                               outTr, blockIdx.x * 64, blockIdx.y * 64, As, Bs);
    }
}

// zero the trace output (atomic accumulation target)
__global__ __launch_bounds__(256) void zero_tr(float* __restrict__ out_tr)
{
    int i = (blockIdx.x * 256 + threadIdx.x) * 4;
    *(float4*)(out_tr + i) = make_float4(0.f, 0.f, 0.f, 0.f);
}

extern "C" void kernel_launch(void* const* d_in, const int* in_sizes, int n_in,
                              void* d_out, int out_size, void* d_ws, size_t ws_size,
                              hipStream_t stream)
{
    const float* z  = (const float*)d_in[0];
    const float* t  = (const float*)d_in[2];
    const float* W1 = (const float*)d_in[3];
    const float* b1 = (const float*)d_in[4];
    const float* W2 = (const float*)d_in[5];
    const float* b2 = (const float*)d_in[6];
    const float* W3 = (const float*)d_in[7];
    const float* b3 = (const float*)d_in[8];
    float* out = (float*)d_out;                 // v [4096*64] then dlogp [4096]
    float* out_tr = out + (size_t)BB * DD;

    char* w = (char*)d_ws;
    auto alloc = [&](size_t bytes) {
        char* p = w;
        w += (bytes + 255) & ~(size_t)255;
        return p;
    };
    bf16* z_b   = (bf16*)alloc((size_t)BB * DD * 2);
    bf16* W1t   = (bf16*)alloc((size_t)HH * DD * 2);
    bf16* W2t   = (bf16*)alloc((size_t)HH * HH * 2);
    bf16* W3t   = (bf16*)alloc((size_t)DD * HH * 2);
    bf16* Pt    = (bf16*)alloc((size_t)HH * HH * 2);
    float* b1eff = (float*)alloc((size_t)HH * 4);
    bf16* h1b   = (bf16*)alloc((size_t)BB * HH * 2);
    bf16* ab    = (bf16*)alloc((size_t)BB * HH * 2);
    bf16* h2b   = (bf16*)alloc((size_t)BB * HH * 2);
    bf16* bsb   = (bf16*)alloc((size_t)BB * HH * 2);

    // 1) conversions, transposes, P, b1eff (+ zero trace region in parallel)
    prep_kernel<<<dim3(256, 6), 256, 0, stream>>>(z, t, W1, b1, W2, W3,
                                                  z_b, W1t, W2t, W3t, Pt, b1eff);
    zero_tr<<<4, 256, 0, stream>>>(out_tr);
    // 2) layer 1: h1 = tanh(z@W1 + b1eff)
    gemm_kernel<0, 64, 512><<<dim3(BB / 64, HH / 64), 256, 0, stream>>>(
        z_b, W1t, b1eff, h1b, ab, nullptr, nullptr, nullptr);
    // 3) layer 2: h2 = tanh(h1@W2 + b2)
    gemm_kernel<0, 512, 512><<<dim3(BB / 64, HH / 64), 256, 0, stream>>>(
        h1b, W2t, b2, h2b, bsb, nullptr, nullptr, nullptr);
    // 4) layer 3 (v) fused with trace GEMM (atomic row-sums into out_tr)
    gemm_fused<<<dim3(BB / 64, HH / 64 + 1), 256, 0, stream>>>(
        h2b, W3t, b3, out, ab, Pt, bsb, out_tr);
}